// Round 11
// baseline (202.824 us; speedup 1.0000x reference)
//
#include <hip/hip_runtime.h>
#include <hip/hip_bf16.h>

#define BATCH 2
#define SLEN 2048
#define NH 12
#define DM 768
#define DH 64
#define ROWS (BATCH*SLEN)   // 4096
#define NQKV (3*DM)         // 2304
#define NCHUNK 51           // split-K chunks per bh (q-tile=128, chunk = up to 6 k-tiles)

typedef __attribute__((ext_vector_type(8))) short bf16x8;
typedef __attribute__((ext_vector_type(4))) float f32x4;
typedef unsigned short u16;
typedef unsigned int u32;
typedef __attribute__((ext_vector_type(4))) unsigned short u16x4;
typedef __attribute__((ext_vector_type(8))) unsigned short u16x8;

__device__ __forceinline__ u16 f2b(float f) {
    unsigned int u = __builtin_bit_cast(unsigned int, f);
    unsigned int r = (u + 0x7FFFu + ((u >> 16) & 1u)) >> 16;
    return (u16)r;
}
__device__ __forceinline__ float b2f(u16 v) {
    unsigned int u = ((unsigned int)v) << 16;
    return __builtin_bit_cast(float, u);
}

// async global->LDS, 16B per lane. LDS dest = wave-uniform base + lane*16.
__device__ __forceinline__ void gload16(const u16* g, u16* l) {
    __builtin_amdgcn_global_load_lds(
        (const __attribute__((address_space(1))) unsigned int*)g,
        (__attribute__((address_space(3))) unsigned int*)l,
        16, 0, 0);
}

// ---------------- pack kernels ----------------

__global__ __launch_bounds__(256) void pack_x(const float* __restrict__ x, u16* __restrict__ xb) {
    int i = blockIdx.x * 256 + threadIdx.x;
    const float4* xv = (const float4*)x;
    float4 a = xv[i * 2], b = xv[i * 2 + 1];
    u16x8 o;
    o[0] = f2b(a.x); o[1] = f2b(a.y); o[2] = f2b(a.z); o[3] = f2b(a.w);
    o[4] = f2b(b.x); o[5] = f2b(b.y); o[6] = f2b(b.z); o[7] = f2b(b.w);
    *(u16x8*)(xb + (size_t)i * 8) = o;
}

__global__ __launch_bounds__(256) void pack_wqkv(const float* __restrict__ WQ, const float* __restrict__ WK,
                                                 const float* __restrict__ WV, u16* __restrict__ out) {
    __shared__ u16 L[64 * 72];
    int mt = blockIdx.x, h = blockIdx.y, sel = blockIdx.z;
    const float* W = sel == 0 ? WQ : (sel == 1 ? WK : WV);
    const float* src = W + ((size_t)h * DM + mt * 64) * DH;
    int t = threadIdx.x;
    for (int j = 0; j < 4; j++) {
        int i = t + 256 * j;
        int r = i >> 4, cf = i & 15;
        float4 v = ((const float4*)src)[i];
        u16x4 o; o[0] = f2b(v.x); o[1] = f2b(v.y); o[2] = f2b(v.z); o[3] = f2b(v.w);
        *(u16x4*)&L[r * 72 + cf * 4] = o;
    }
    __syncthreads();
    u16* orow = out + ((size_t)(sel * DM + h * DH)) * DM + mt * 64;
    for (int j = 0; j < 16; j++) {
        int e = t + 256 * j;
        int d = e >> 6, mm = e & 63;
        orow[(size_t)d * DM + mm] = L[mm * 72 + d];
    }
}

__global__ __launch_bounds__(256) void pack_wo(const float* __restrict__ WO, u16* __restrict__ out) {
    __shared__ u16 L[64 * 72];
    int bi = blockIdx.x, bj = blockIdx.y;
    int t = threadIdx.x;
    for (int j = 0; j < 4; j++) {
        int i = t + 256 * j;
        int r = i >> 4, cf = i & 15;
        float4 v = ((const float4*)(WO + (size_t)(bi * 64 + r) * DM + bj * 64))[cf];
        u16x4 o; o[0] = f2b(v.x); o[1] = f2b(v.y); o[2] = f2b(v.z); o[3] = f2b(v.w);
        *(u16x4*)&L[r * 72 + cf * 4] = o;
    }
    __syncthreads();
    for (int j = 0; j < 16; j++) {
        int e = t + 256 * j;
        int c = e >> 6, r = e & 63;
        out[(size_t)(bj * 64 + c) * DM + bi * 64 + r] = L[r * 72 + c];
    }
}

// ---------------- QKV GEMM (128x128, global_load_lds staging, XOR-swizzled LDS) ----

__global__ __launch_bounds__(256) void gemm_qkv(const u16* __restrict__ A, const u16* __restrict__ Bt,
                                                const float* __restrict__ bQ, const float* __restrict__ bK,
                                                const float* __restrict__ bV,
                                                u16* __restrict__ Qb, u16* __restrict__ Kb, u16* __restrict__ Vb) {
    __shared__ u16 Al[128 * 64];
    __shared__ u16 Bl[128 * 64];
    int t = threadIdx.x;
    int n0 = blockIdx.x * 128, m0 = blockIdx.y * 128;
    int lane = t & 63, w = t >> 6;
    int ln = lane & 15, qd = lane >> 4;
    int wr = (w & 1) * 64, wc = (w >> 1) * 64;
    int srow = lane >> 3, slot = lane & 7;
    f32x4 acc[4][4] = {};

    for (int kt = 0; kt < DM / 64; kt++) {
        __syncthreads();
        for (int j = 0; j < 4; j++) {
            int r = w * 32 + j * 8 + srow;
            int gc = slot ^ (r & 7);
            gload16(A + (size_t)(m0 + r) * DM + kt * 64 + gc * 8, &Al[(w * 32 + j * 8) * 64]);
            gload16(Bt + (size_t)(n0 + r) * DM + kt * 64 + gc * 8, &Bl[(w * 32 + j * 8) * 64]);
        }
        __syncthreads();
        for (int ks = 0; ks < 2; ks++) {
            int sl = ((ks * 4 + qd) ^ (ln & 7)) * 8;
            bf16x8 af[4], bfr[4];
            for (int rt = 0; rt < 4; rt++)
                af[rt] = *(const bf16x8*)&Al[(wr + rt * 16 + ln) * 64 + sl];
            for (int ct = 0; ct < 4; ct++)
                bfr[ct] = *(const bf16x8*)&Bl[(wc + ct * 16 + ln) * 64 + sl];
            for (int rt = 0; rt < 4; rt++)
                for (int ct = 0; ct < 4; ct++)
                    acc[rt][ct] = __builtin_amdgcn_mfma_f32_16x16x32_bf16(af[rt], bfr[ct], acc[rt][ct], 0, 0, 0);
        }
    }
    int sel = n0 / DM;
    if (sel == 2) {
        for (int ct = 0; ct < 4; ct++) {
            int col = n0 - 2 * DM + wc + ct * 16 + ln;
            int hh = col >> 6, dd = col & 63;
            float bv = bV[col];
            for (int rt = 0; rt < 4; rt++) {
                int row = m0 + wr + rt * 16 + qd * 4;
                int bb = row >> 11, ss = row & 2047;
                u16x4 pk;
                for (int r = 0; r < 4; r++) pk[r] = f2b(acc[rt][ct][r] + bv);
                *(u16x4*)&Vb[(((size_t)bb * NH + hh) * DH + dd) * SLEN + ss] = pk;
            }
        }
    } else {
        const float* bias = sel == 0 ? bQ : bK;
        u16* Out = sel == 0 ? Qb : Kb;
        const float qs = sel == 0 ? 0.125f * 1.44269504f : 1.0f;
        for (int ct = 0; ct < 4; ct++) {
            int col = n0 - sel * DM + wc + ct * 16 + ln;
            int hh = col >> 6, dd = col & 63;
            float bv = bias[col];
            for (int rt = 0; rt < 4; rt++) {
                int row = m0 + wr + rt * 16 + qd * 4;
                for (int r = 0; r < 4; r++) {
                    int rg = row + r;
                    int bb = rg >> 11, ss = rg & 2047;
                    Out[(((size_t)bb * NH + hh) * SLEN + ss) * DH + dd] = f2b((acc[rt][ct][r] + bv) * qs);
                }
            }
        }
    }
}

// ---------------- split-K flash attention: q=128, double-buffered gload16, XCD-local bh ----
// 1D grid 1224: j = blk%24 -> bh = (j&7)*3 + (j>>3)  (51 chunks of a bh share an XCD),
// cid = blk/24 -> (p, c, nc) with nc = p/3+1 (chunks of <=6 k-tiles).
// Single barrier per k-iteration: loads for kt+1 issued after the barrier that
// publishes tile kt, overlap with tile kt's compute. LDS 40 KB -> 4 blocks/CU.

__device__ __forceinline__ void cid2qc(int cid, int& p, int& c, int& nc) {
    p = 0;
    int base = 0;
    while (true) {
        int n = p / 3 + 1;
        if (cid < base + n) { c = cid - base; nc = n; return; }
        base += n; p++;
    }
}

__global__ __launch_bounds__(256, 4) void attn(const u16* __restrict__ Qb, const u16* __restrict__ Kb,
                                               const u16* __restrict__ Vtg,
                                               u16* __restrict__ Po, float* __restrict__ Plv) {
    __shared__ u16 Kl[2][64 * 64];       // [buf][k][d], 16B chunks XOR-swizzled by row&7
    __shared__ u16 Vt[2][64 * 64];       // [buf][d][k], swizzled
    __shared__ u16 Pq[4][16 * 64];       // wave-private P^T, reused for fragments A and B (8 KB)
    int blk = blockIdx.x;
    int j24 = blk % 24;
    int cid = blk / 24;
    int bh = (j24 & 7) * 3 + (j24 >> 3);
    int p, c, nc;
    cid2qc(cid, p, c, nc);
    int ntiles = 2 * p + 2;
    int kt0 = c * ntiles / nc, kt1 = (c + 1) * ntiles / nc;
    const u16* Qp = Qb + (size_t)bh * SLEN * DH;
    const u16* Kp = Kb + (size_t)bh * SLEN * DH;
    const u16* Vp = Vtg + (size_t)bh * SLEN * DH;  // [d][s]
    int t = threadIdx.x, lane = t & 63, w = t >> 6;
    int ln = lane & 15, qd = lane >> 4;
    int srow = lane >> 3, slot = lane & 7;
    int qbA = p * 128 + w * 32, qbB = qbA + 16;

    bf16x8 qfA[2], qfB[2];
    for (int ks = 0; ks < 2; ks++) {
        qfA[ks] = *(const bf16x8*)(Qp + (size_t)(qbA + ln) * DH + ks * 32 + qd * 8);
        qfB[ks] = *(const bf16x8*)(Qp + (size_t)(qbB + ln) * DH + ks * 32 + qd * 8);
    }

    float lA = 0.f, lB = 0.f;
    f32x4 oA[4] = {}, oB[4] = {};
    u16* Pw = Pq[w];
    int cur = 0;

    auto stage = [&](int kt, int buf) {
        int k0 = kt * 64;
        for (int j = 0; j < 2; j++) {
            int r = w * 16 + j * 8 + srow;
            int gc = slot ^ (r & 7);
            gload16(Kp + (size_t)(k0 + r) * DH + gc * 8, &Kl[buf][(w * 16 + j * 8) * 64]);
            gload16(Vp + (size_t)r * SLEN + k0 + gc * 8, &Vt[buf][(w * 16 + j * 8) * 64]);
        }
    };

    // softmax (exp2 + truncate-to-bf16, consistent for P and l) + PV for one fragment.
    // Pw reuse across fragments is safe: same-wave DS ops are in-order.
    auto frag = [&](f32x4 (&sf)[4], float& l, f32x4 (&o)[4]) {
        float s = 0.f;
        for (int ct = 0; ct < 4; ct++) {
            u32 e4[4];
            for (int r = 0; r < 4; r++) {
                float e = exp2f(sf[ct][r]);
                e4[r] = __builtin_bit_cast(u32, e);
                s += __builtin_bit_cast(float, e4[r] & 0xFFFF0000u);
            }
            uint2 pk;
            pk.x = __builtin_amdgcn_perm(e4[1], e4[0], 0x07060302u);
            pk.y = __builtin_amdgcn_perm(e4[3], e4[2], 0x07060302u);
            int off = (((ct * 2 + (qd >> 1)) ^ (ln & 7)) * 8) + (qd & 1) * 4;
            *(uint2*)&Pw[ln * 64 + off] = pk;
        }
        l += s;
        for (int ks = 0; ks < 2; ks++) {
            int sl = ((ks * 4 + qd) ^ (ln & 7)) * 8;
            bf16x8 pf = *(const bf16x8*)&Pw[ln * 64 + sl];
            for (int dt = 0; dt < 4; dt++) {
                bf16x8 vf = *(const bf16x8*)&Vt[cur][(dt * 16 + ln) * 64 + sl];
                o[dt] = __builtin_amdgcn_mfma_f32_16x16x32_bf16(vf, pf, o[dt], 0, 0, 0);
            }
        }
    };

    stage(kt0, 0);
    for (int kt = kt0; kt < kt1; kt++) {
        cur = (kt - kt0) & 1;
        int k0 = kt * 64;
        __syncthreads();                 // publishes buf cur (drains its loads); prior readers of cur^1 are done
        if (kt + 1 < kt1) stage(kt + 1, cur ^ 1);

        // S^T = K Q^T for both q-fragments, sharing K-fragment loads
        f32x4 sfA[4] = {}, sfB[4] = {};
        for (int ks = 0; ks < 2; ks++) {
            int sl = ((ks * 4 + qd) ^ (ln & 7)) * 8;
            for (int ct = 0; ct < 4; ct++) {
                bf16x8 kf = *(const bf16x8*)&Kl[cur][(ct * 16 + ln) * 64 + sl];
                sfA[ct] = __builtin_amdgcn_mfma_f32_16x16x32_bf16(kf, qfA[ks], sfA[ct], 0, 0, 0);
                sfB[ct] = __builtin_amdgcn_mfma_f32_16x16x32_bf16(kf, qfB[ks], sfB[ct], 0, 0, 0);
            }
        }

        // causal mask per fragment (wave-uniform branch)
        if (kt >= (qbA >> 6)) {
            int qg = qbA + ln;
            for (int ct = 0; ct < 4; ct++)
                for (int r = 0; r < 4; r++) {
                    int kg = k0 + ct * 16 + qd * 4 + r;
                    if (kg > qg) sfA[ct][r] = -1e30f;
                }
        }
        if (kt >= (qbB >> 6)) {
            int qg = qbB + ln;
            for (int ct = 0; ct < 4; ct++)
                for (int r = 0; r < 4; r++) {
                    int kg = k0 + ct * 16 + qd * 4 + r;
                    if (kg > qg) sfB[ct][r] = -1e30f;
                }
        }

        frag(sfA, lA, oA);
        frag(sfB, lB, oB);
    }

    lA += __shfl_xor(lA, 16, 64);
    lA += __shfl_xor(lA, 32, 64);
    lB += __shfl_xor(lB, 16, 64);
    lB += __shfl_xor(lB, 32, 64);

    // partial: o bf16 [q-local 128][64 d], l f32 [128]
    size_t pid = (size_t)bh * NCHUNK + cid;
    u16* op = Po + pid * 8192;
    for (int dt = 0; dt < 4; dt++) {
        u16x4 ovA, ovB;
        for (int r = 0; r < 4; r++) { ovA[r] = f2b(oA[dt][r]); ovB[r] = f2b(oB[dt][r]); }
        *(u16x4*)&op[(w * 32 + ln) * 64 + dt * 16 + qd * 4] = ovA;
        *(u16x4*)&op[(w * 32 + 16 + ln) * 64 + dt * 16 + qd * 4] = ovB;
    }
    if (qd == 0) {
        Plv[pid * 128 + w * 32 + ln] = lA;
        Plv[pid * 128 + w * 32 + 16 + ln] = lB;
    }
}

// ---------------- combine partials -> Z bf16 [4096][768] ----------------

__global__ __launch_bounds__(256) void combine(const u16* __restrict__ Po, const float* __restrict__ Plv,
                                               u16* __restrict__ Zb) {
    int p = blockIdx.x, bh = blockIdx.y;
    int b = bh / NH, h = bh % NH;
    int g = p / 3, i = p % 3;
    int nc = g + 1;
    int base = 3 * (g * (g + 1) / 2) + i * (g + 1);
    int t = threadIdx.x;
    int q = t >> 1, dseg = (t & 1) * 32;

    float acc[32] = {};
    float lsum = 0.f;
    for (int cc = 0; cc < nc; cc++) {
        size_t pid = (size_t)bh * NCHUNK + base + cc;
        lsum += Plv[pid * 128 + q];
        const u16* op = Po + pid * 8192 + q * 64 + dseg;
        for (int j = 0; j < 4; j++) {
            u16x8 v = *(const u16x8*)(op + j * 8);
            for (int e = 0; e < 8; e++)
                acc[j * 8 + e] += b2f(v[e]);
        }
    }
    float inv = 1.0f / lsum;
    u16* Zp = Zb + ((size_t)b * SLEN + p * 128 + q) * DM + h * DH + dseg;
    for (int j = 0; j < 4; j++) {
        u16x8 ov;
        for (int e = 0; e < 8; e++) ov[e] = f2b(acc[j * 8 + e] * inv);
        *(u16x8*)(Zp + j * 8) = ov;
    }
}

// ---------------- output projection (64x96 tile, global_load_lds staging) ----------------

__global__ __launch_bounds__(256) void gemm_proj(const u16* __restrict__ A, const u16* __restrict__ Bt,
                                                 const float* __restrict__ bO, float* __restrict__ out) {
    __shared__ u16 Al[64 * 64];
    __shared__ u16 Bl[96 * 64];
    int t = threadIdx.x;
    int n0 = blockIdx.x * 96, m0 = blockIdx.y * 64;
    int lane = t & 63, w = t >> 6;
    int ln = lane & 15, qd = lane >> 4;
    int wr = (w & 1) * 32, wc = (w >> 1) * 48;
    int srow = lane >> 3, slot = lane & 7;
    f32x4 acc[2][3] = {};

    for (int kt = 0; kt < DM / 64; kt++) {
        __syncthreads();
        for (int j = 0; j < 2; j++) {
            int r = w * 16 + j * 8 + srow;
            int gc = slot ^ (r & 7);
            gload16(A + (size_t)(m0 + r) * DM + kt * 64 + gc * 8, &Al[(w * 16 + j * 8) * 64]);
        }
        for (int j = 0; j < 3; j++) {
            int r = w * 24 + j * 8 + srow;
            int gc = slot ^ (r & 7);
            gload16(Bt + (size_t)(n0 + r) * DM + kt * 64 + gc * 8, &Bl[(w * 24 + j * 8) * 64]);
        }
        __syncthreads();
        for (int ks = 0; ks < 2; ks++) {
            int sl = ((ks * 4 + qd) ^ (ln & 7)) * 8;
            bf16x8 af[2], bfr[3];
            for (int rt = 0; rt < 2; rt++)
                af[rt] = *(const bf16x8*)&Al[(wr + rt * 16 + ln) * 64 + sl];
            for (int ct = 0; ct < 3; ct++)
                bfr[ct] = *(const bf16x8*)&Bl[(wc + ct * 16 + ln) * 64 + sl];
            for (int rt = 0; rt < 2; rt++)
                for (int ct = 0; ct < 3; ct++)
                    acc[rt][ct] = __builtin_amdgcn_mfma_f32_16x16x32_bf16(af[rt], bfr[ct], acc[rt][ct], 0, 0, 0);
        }
    }
    for (int ct = 0; ct < 3; ct++) {
        int col = n0 + wc + ct * 16 + ln;
        float bv = bO[col];
        for (int rt = 0; rt < 2; rt++) {
            int row = m0 + wr + rt * 16 + qd * 4;
            for (int r = 0; r < 4; r++)
                out[(size_t)(row + r) * DM + col] = acc[rt][ct][r] + bv;
        }
    }
}

// ---------------- launch ----------------

extern "C" void kernel_launch(void* const* d_in, const int* in_sizes, int n_in,
                              void* d_out, int out_size, void* d_ws, size_t ws_size,
                              hipStream_t stream) {
    const float* x  = (const float*)d_in[0];
    const float* WQ = (const float*)d_in[1];
    const float* bQ = (const float*)d_in[2];
    const float* WK = (const float*)d_in[3];
    const float* bK = (const float*)d_in[4];
    const float* WV = (const float*)d_in[5];
    const float* bV = (const float*)d_in[6];
    const float* WO = (const float*)d_in[7];
    const float* bO = (const float*)d_in[8];
    float* out = (float*)d_out;

    u16* xb   = (u16*)d_ws;                        // [4096][768]
    u16* wqkv = xb + (size_t)ROWS * DM;            // [2304][768]
    u16* wo   = wqkv + (size_t)NQKV * DM;          // [768][768]
    u16* Qb   = wo + (size_t)DM * DM;
    size_t hsz = (size_t)BATCH * NH * SLEN * DH;
    u16* Kb   = Qb + hsz;
    u16* Vb   = Kb + hsz;                          // V^T [b,h,d,s]
    u16* Zb   = Vb + hsz;                          // [4096][768]
    u16* Po   = Zb + (size_t)ROWS * DM;            // partials o: [24*51][128][64] bf16
    float* Pl = (float*)(Po + (size_t)BATCH * NH * NCHUNK * 8192);

    pack_x<<<ROWS * DM / 2048, 256, 0, stream>>>(x, xb);
    pack_wqkv<<<dim3(12, 12, 3), 256, 0, stream>>>(WQ, WK, WV, wqkv);
    pack_wo<<<dim3(12, 12), 256, 0, stream>>>(WO, wo);
    gemm_qkv<<<dim3(NQKV / 128, ROWS / 128), 256, 0, stream>>>(xb, wqkv, bQ, bK, bV, Qb, Kb, Vb);
    attn<<<dim3(NCHUNK * 24), 256, 0, stream>>>(Qb, Kb, Vb, Po, Pl);
    combine<<<dim3(SLEN / 128, BATCH * NH), 256, 0, stream>>>(Po, Pl, Zb);
    gemm_proj<<<dim3(DM / 96, ROWS / 64), 256, 0, stream>>>(Zb, wo, bO, out);
}

// Round 12
// 170.832 us; speedup vs baseline: 1.1873x; 1.1873x over previous
//
#include <hip/hip_runtime.h>
#include <hip/hip_bf16.h>

#define BATCH 2
#define SLEN 2048
#define NH 12
#define DM 768
#define DH 64
#define ROWS (BATCH*SLEN)   // 4096
#define NQKV (3*DM)         // 2304
#define NCHUNK 80           // split-K chunks per bh (q-tile=64, chunk = up to 8 k-tiles)

typedef __attribute__((ext_vector_type(8))) short bf16x8;
typedef __attribute__((ext_vector_type(4))) float f32x4;
typedef unsigned short u16;
typedef unsigned int u32;
typedef __attribute__((ext_vector_type(4))) unsigned short u16x4;
typedef __attribute__((ext_vector_type(8))) unsigned short u16x8;

__device__ __forceinline__ u16 f2b(float f) {
    unsigned int u = __builtin_bit_cast(unsigned int, f);
    unsigned int r = (u + 0x7FFFu + ((u >> 16) & 1u)) >> 16;
    return (u16)r;
}
__device__ __forceinline__ float b2f(u16 v) {
    unsigned int u = ((unsigned int)v) << 16;
    return __builtin_bit_cast(float, u);
}

// async global->LDS, 16B per lane. LDS dest = wave-uniform base + lane*16.
__device__ __forceinline__ void gload16(const u16* g, u16* l) {
    __builtin_amdgcn_global_load_lds(
        (const __attribute__((address_space(1))) unsigned int*)g,
        (__attribute__((address_space(3))) unsigned int*)l,
        16, 0, 0);
}

// ---------------- pack kernels ----------------

__global__ __launch_bounds__(256) void pack_x(const float* __restrict__ x, u16* __restrict__ xb) {
    int i = blockIdx.x * 256 + threadIdx.x;
    const float4* xv = (const float4*)x;
    float4 a = xv[i * 2], b = xv[i * 2 + 1];
    u16x8 o;
    o[0] = f2b(a.x); o[1] = f2b(a.y); o[2] = f2b(a.z); o[3] = f2b(a.w);
    o[4] = f2b(b.x); o[5] = f2b(b.y); o[6] = f2b(b.z); o[7] = f2b(b.w);
    *(u16x8*)(xb + (size_t)i * 8) = o;
}

__global__ __launch_bounds__(256) void pack_wqkv(const float* __restrict__ WQ, const float* __restrict__ WK,
                                                 const float* __restrict__ WV, u16* __restrict__ out) {
    __shared__ u16 L[64 * 72];
    int mt = blockIdx.x, h = blockIdx.y, sel = blockIdx.z;
    const float* W = sel == 0 ? WQ : (sel == 1 ? WK : WV);
    const float* src = W + ((size_t)h * DM + mt * 64) * DH;
    int t = threadIdx.x;
    for (int j = 0; j < 4; j++) {
        int i = t + 256 * j;
        int r = i >> 4, cf = i & 15;
        float4 v = ((const float4*)src)[i];
        u16x4 o; o[0] = f2b(v.x); o[1] = f2b(v.y); o[2] = f2b(v.z); o[3] = f2b(v.w);
        *(u16x4*)&L[r * 72 + cf * 4] = o;
    }
    __syncthreads();
    u16* orow = out + ((size_t)(sel * DM + h * DH)) * DM + mt * 64;
    for (int j = 0; j < 16; j++) {
        int e = t + 256 * j;
        int d = e >> 6, mm = e & 63;
        orow[(size_t)d * DM + mm] = L[mm * 72 + d];
    }
}

__global__ __launch_bounds__(256) void pack_wo(const float* __restrict__ WO, u16* __restrict__ out) {
    __shared__ u16 L[64 * 72];
    int bi = blockIdx.x, bj = blockIdx.y;
    int t = threadIdx.x;
    for (int j = 0; j < 4; j++) {
        int i = t + 256 * j;
        int r = i >> 4, cf = i & 15;
        float4 v = ((const float4*)(WO + (size_t)(bi * 64 + r) * DM + bj * 64))[cf];
        u16x4 o; o[0] = f2b(v.x); o[1] = f2b(v.y); o[2] = f2b(v.z); o[3] = f2b(v.w);
        *(u16x4*)&L[r * 72 + cf * 4] = o;
    }
    __syncthreads();
    for (int j = 0; j < 16; j++) {
        int e = t + 256 * j;
        int c = e >> 6, r = e & 63;
        out[(size_t)(bj * 64 + c) * DM + bi * 64 + r] = L[r * 72 + c];
    }
}

// ---------------- QKV GEMM (128x128, global_load_lds staging, XOR-swizzled LDS) ----
// LDS layout: [row][64 u16], 16B chunk c of row r stored at slot c^(r&7).
// -> Q(pre-scaled by 0.125*log2e)/K [b,h,s,d], V^T [b,h,d,s]

__global__ __launch_bounds__(256) void gemm_qkv(const u16* __restrict__ A, const u16* __restrict__ Bt,
                                                const float* __restrict__ bQ, const float* __restrict__ bK,
                                                const float* __restrict__ bV,
                                                u16* __restrict__ Qb, u16* __restrict__ Kb, u16* __restrict__ Vb) {
    __shared__ u16 Al[128 * 64];
    __shared__ u16 Bl[128 * 64];
    int t = threadIdx.x;
    int n0 = blockIdx.x * 128, m0 = blockIdx.y * 128;
    int lane = t & 63, w = t >> 6;
    int ln = lane & 15, qd = lane >> 4;
    int wr = (w & 1) * 64, wc = (w >> 1) * 64;
    int srow = lane >> 3, slot = lane & 7;
    f32x4 acc[4][4] = {};

    for (int kt = 0; kt < DM / 64; kt++) {
        __syncthreads();
        for (int j = 0; j < 4; j++) {
            int r = w * 32 + j * 8 + srow;
            int gc = slot ^ (r & 7);
            gload16(A + (size_t)(m0 + r) * DM + kt * 64 + gc * 8, &Al[(w * 32 + j * 8) * 64]);
            gload16(Bt + (size_t)(n0 + r) * DM + kt * 64 + gc * 8, &Bl[(w * 32 + j * 8) * 64]);
        }
        __syncthreads();   // drains vmcnt -> tile visible
        for (int ks = 0; ks < 2; ks++) {
            int sl = ((ks * 4 + qd) ^ (ln & 7)) * 8;
            bf16x8 af[4], bfr[4];
            for (int rt = 0; rt < 4; rt++)
                af[rt] = *(const bf16x8*)&Al[(wr + rt * 16 + ln) * 64 + sl];
            for (int ct = 0; ct < 4; ct++)
                bfr[ct] = *(const bf16x8*)&Bl[(wc + ct * 16 + ln) * 64 + sl];
            for (int rt = 0; rt < 4; rt++)
                for (int ct = 0; ct < 4; ct++)
                    acc[rt][ct] = __builtin_amdgcn_mfma_f32_16x16x32_bf16(af[rt], bfr[ct], acc[rt][ct], 0, 0, 0);
        }
    }
    int sel = n0 / DM;
    if (sel == 2) {
        for (int ct = 0; ct < 4; ct++) {
            int col = n0 - 2 * DM + wc + ct * 16 + ln;
            int hh = col >> 6, dd = col & 63;
            float bv = bV[col];
            for (int rt = 0; rt < 4; rt++) {
                int row = m0 + wr + rt * 16 + qd * 4;
                int bb = row >> 11, ss = row & 2047;
                u16x4 pk;
                for (int r = 0; r < 4; r++) pk[r] = f2b(acc[rt][ct][r] + bv);
                *(u16x4*)&Vb[(((size_t)bb * NH + hh) * DH + dd) * SLEN + ss] = pk;
            }
        }
    } else {
        const float* bias = sel == 0 ? bQ : bK;
        u16* Out = sel == 0 ? Qb : Kb;
        const float qs = sel == 0 ? 0.125f * 1.44269504f : 1.0f;
        for (int ct = 0; ct < 4; ct++) {
            int col = n0 - sel * DM + wc + ct * 16 + ln;
            int hh = col >> 6, dd = col & 63;
            float bv = bias[col];
            for (int rt = 0; rt < 4; rt++) {
                int row = m0 + wr + rt * 16 + qd * 4;
                for (int r = 0; r < 4; r++) {
                    int rg = row + r;
                    int bb = rg >> 11, ss = rg & 2047;
                    Out[(((size_t)bb * NH + hh) * SLEN + ss) * DH + dd] = f2b((acc[rt][ct][r] + bv) * qs);
                }
            }
        }
    }
}

// ---------------- split-K flash attention (R7 form) + XCD-local bh mapping ----
// 1D grid 1920: cid = blk/24; j24 = blk%24 -> bh = (j24&7)*3 + (j24>>3), so blocks
// with equal blk%8 (same XCD under round-robin) serve only 3 bh -> K/V L2-resident.
// q-tile=64, 4 waves x 16 q-rows, register preload (44 VGPR, below spill cliff).

__device__ __forceinline__ void cid2qc(int cid, int& qt, int& c, int& nc) {
    if (cid < 8)       { qt = cid;                 c = 0;              nc = 1; }
    else if (cid < 24) { qt = 8 + ((cid - 8) >> 1); c = (cid - 8) & 1; nc = 2; }
    else if (cid < 48) { qt = 16 + (cid - 24) / 3;  c = (cid - 24) % 3; nc = 3; }
    else               { qt = 24 + ((cid - 48) >> 2); c = (cid - 48) & 3; nc = 4; }
}

__global__ __launch_bounds__(256, 4) void attn(const u16* __restrict__ Qb, const u16* __restrict__ Kb,
                                               const u16* __restrict__ Vtg,
                                               u16* __restrict__ Po, float* __restrict__ Plv) {
    __shared__ u16 Kl[64 * 72];
    __shared__ u16 Vt[64 * 72];          // [d][k]
    __shared__ u16 Pq[4][16 * 72];       // wave-private P: [q-local][k]
    int blk = blockIdx.x;
    int cid = blk / 24;
    int j24 = blk % 24;
    int bh = (j24 & 7) * 3 + (j24 >> 3);
    int qt, c, nc;
    cid2qc(cid, qt, c, nc);
    int ntiles = qt + 1;
    int kt0 = c * ntiles / nc, kt1 = (c + 1) * ntiles / nc;
    const u16* Qp = Qb + (size_t)bh * SLEN * DH;
    const u16* Kp = Kb + (size_t)bh * SLEN * DH;
    const u16* Vp = Vtg + (size_t)bh * SLEN * DH;  // [d][s]
    int t = threadIdx.x, lane = t & 63, w = t >> 6;
    int ln = lane & 15, qd = lane >> 4;
    int qw = qt * 64 + w * 16;

    bf16x8 qf[2];
    for (int ks = 0; ks < 2; ks++)
        qf[ks] = *(const bf16x8*)(Qp + (size_t)(qw + ln) * DH + ks * 32 + qd * 8);

    float l = 0.f;
    f32x4 o[4] = {};

    u16x8 kr[2], vr[2];
    int sr = t >> 3, scf = t & 7;
    auto preload = [&](int kt) {
        int k0 = kt * 64;
        for (int j = 0; j < 2; j++) {
            int r = sr + 32 * j;
            kr[j] = *(const u16x8*)(Kp + (size_t)(k0 + r) * DH + scf * 8);
            vr[j] = *(const u16x8*)(Vp + (size_t)r * SLEN + k0 + scf * 8);
        }
    };
    preload(kt0);

    u16* Pw = Pq[w];
    for (int kt = kt0; kt < kt1; kt++) {
        __syncthreads();
        for (int j = 0; j < 2; j++) {
            int r = sr + 32 * j;
            *(u16x8*)&Kl[r * 72 + scf * 8] = kr[j];
            *(u16x8*)&Vt[r * 72 + scf * 8] = vr[j];
        }
        __syncthreads();
        if (kt + 1 < kt1) preload(kt + 1);

        f32x4 sf[4] = {};
        for (int ks = 0; ks < 2; ks++)
            for (int ct = 0; ct < 4; ct++) {
                bf16x8 kf = *(const bf16x8*)&Kl[(ct * 16 + ln) * 72 + ks * 32 + qd * 8];
                sf[ct] = __builtin_amdgcn_mfma_f32_16x16x32_bf16(kf, qf[ks], sf[ct], 0, 0, 0);
            }

        if (kt == qt) {
            int qg = qw + ln;
            for (int ct = 0; ct < 4; ct++)
                for (int r = 0; r < 4; r++) {
                    int kg = kt * 64 + ct * 16 + qd * 4 + r;
                    if (kg > qg) sf[ct][r] = -1e30f;
                }
        }

        float s = 0.f;
        for (int ct = 0; ct < 4; ct++) {
            u32 eb[4];
            for (int r = 0; r < 4; r++) {
                float e = exp2f(sf[ct][r]);
                u32 ub = __builtin_bit_cast(u32, e) & 0xFFFF0000u;
                eb[r] = __builtin_bit_cast(u32, e);
                s += __builtin_bit_cast(float, ub);
            }
            u32 p01 = __builtin_amdgcn_perm(eb[1], eb[0], 0x07060302u);
            u32 p23 = __builtin_amdgcn_perm(eb[3], eb[2], 0x07060302u);
            uint2 pk; pk.x = p01; pk.y = p23;
            *(uint2*)&Pw[ln * 72 + ct * 16 + qd * 4] = pk;
        }
        l += s;

        for (int ks = 0; ks < 2; ks++) {
            bf16x8 pf = *(const bf16x8*)&Pw[ln * 72 + ks * 32 + qd * 8];
            for (int dt = 0; dt < 4; dt++) {
                bf16x8 vf = *(const bf16x8*)&Vt[(dt * 16 + ln) * 72 + ks * 32 + qd * 8];
                o[dt] = __builtin_amdgcn_mfma_f32_16x16x32_bf16(vf, pf, o[dt], 0, 0, 0);
            }
        }
    }

    l += __shfl_xor(l, 16, 64);
    l += __shfl_xor(l, 32, 64);

    size_t pid = (size_t)bh * NCHUNK + cid;
    u16* op = Po + pid * 4096;
    for (int dt = 0; dt < 4; dt++) {
        u16x4 ov;
        ov[0] = f2b(o[dt][0]); ov[1] = f2b(o[dt][1]);
        ov[2] = f2b(o[dt][2]); ov[3] = f2b(o[dt][3]);
        *(u16x4*)&op[(w * 16 + ln) * 64 + dt * 16 + qd * 4] = ov;
    }
    if (qd == 0)
        Plv[pid * 64 + w * 16 + ln] = l;
}

// ---------------- combine partials -> Z bf16 [4096][768] ----------------

__global__ __launch_bounds__(256) void combine(const u16* __restrict__ Po, const float* __restrict__ Plv,
                                               u16* __restrict__ Zb) {
    int qt = blockIdx.x, bh = blockIdx.y;
    int b = bh / NH, h = bh % NH;
    int nc = (qt >> 3) + 1;
    int base;
    if (qt < 8) base = qt;
    else if (qt < 16) base = 8 + (qt - 8) * 2;
    else if (qt < 24) base = 24 + (qt - 16) * 3;
    else base = 48 + (qt - 24) * 4;
    int t = threadIdx.x;
    int q = t >> 2, dseg = (t & 3) * 16;

    float acc[16] = {};
    float lsum = 0.f;
    for (int cc = 0; cc < nc; cc++) {
        size_t pid = (size_t)bh * NCHUNK + base + cc;
        lsum += Plv[pid * 64 + q];
        const u16* op = Po + pid * 4096 + q * 64 + dseg;
        for (int j = 0; j < 2; j++) {
            u16x8 v = *(const u16x8*)(op + j * 8);
            for (int e = 0; e < 8; e++)
                acc[j * 8 + e] += b2f(v[e]);
        }
    }
    float inv = 1.0f / lsum;
    u16* Zp = Zb + ((size_t)b * SLEN + qt * 64 + q) * DM + h * DH + dseg;
    u16x8 ov;
    for (int j = 0; j < 2; j++) {
        for (int e = 0; e < 8; e++) ov[e] = f2b(acc[j * 8 + e] * inv);
        *(u16x8*)(Zp + j * 8) = ov;
    }
}

// ---------------- output projection (64x96 tile, global_load_lds staging) ----------------
// grid (8, 64) = 512 blocks = 2.0 blocks/CU exact.

__global__ __launch_bounds__(256) void gemm_proj(const u16* __restrict__ A, const u16* __restrict__ Bt,
                                                 const float* __restrict__ bO, float* __restrict__ out) {
    __shared__ u16 Al[64 * 64];
    __shared__ u16 Bl[96 * 64];
    int t = threadIdx.x;
    int n0 = blockIdx.x * 96, m0 = blockIdx.y * 64;
    int lane = t & 63, w = t >> 6;
    int ln = lane & 15, qd = lane >> 4;
    int wr = (w & 1) * 32, wc = (w >> 1) * 48;
    int srow = lane >> 3, slot = lane & 7;
    f32x4 acc[2][3] = {};

    for (int kt = 0; kt < DM / 64; kt++) {
        __syncthreads();
        for (int j = 0; j < 2; j++) {
            int r = w * 16 + j * 8 + srow;
            int gc = slot ^ (r & 7);
            gload16(A + (size_t)(m0 + r) * DM + kt * 64 + gc * 8, &Al[(w * 16 + j * 8) * 64]);
        }
        for (int j = 0; j < 3; j++) {
            int r = w * 24 + j * 8 + srow;
            int gc = slot ^ (r & 7);
            gload16(Bt + (size_t)(n0 + r) * DM + kt * 64 + gc * 8, &Bl[(w * 24 + j * 8) * 64]);
        }
        __syncthreads();
        for (int ks = 0; ks < 2; ks++) {
            int sl = ((ks * 4 + qd) ^ (ln & 7)) * 8;
            bf16x8 af[2], bfr[3];
            for (int rt = 0; rt < 2; rt++)
                af[rt] = *(const bf16x8*)&Al[(wr + rt * 16 + ln) * 64 + sl];
            for (int ct = 0; ct < 3; ct++)
                bfr[ct] = *(const bf16x8*)&Bl[(wc + ct * 16 + ln) * 64 + sl];
            for (int rt = 0; rt < 2; rt++)
                for (int ct = 0; ct < 3; ct++)
                    acc[rt][ct] = __builtin_amdgcn_mfma_f32_16x16x32_bf16(af[rt], bfr[ct], acc[rt][ct], 0, 0, 0);
        }
    }
    for (int ct = 0; ct < 3; ct++) {
        int col = n0 + wc + ct * 16 + ln;
        float bv = bO[col];
        for (int rt = 0; rt < 2; rt++) {
            int row = m0 + wr + rt * 16 + qd * 4;
            for (int r = 0; r < 4; r++)
                out[(size_t)(row + r) * DM + col] = acc[rt][ct][r] + bv;
        }
    }
}

// ---------------- launch ----------------

extern "C" void kernel_launch(void* const* d_in, const int* in_sizes, int n_in,
                              void* d_out, int out_size, void* d_ws, size_t ws_size,
                              hipStream_t stream) {
    const float* x  = (const float*)d_in[0];
    const float* WQ = (const float*)d_in[1];
    const float* bQ = (const float*)d_in[2];
    const float* WK = (const float*)d_in[3];
    const float* bK = (const float*)d_in[4];
    const float* WV = (const float*)d_in[5];
    const float* bV = (const float*)d_in[6];
    const float* WO = (const float*)d_in[7];
    const float* bO = (const float*)d_in[8];
    float* out = (float*)d_out;

    u16* xb   = (u16*)d_ws;                        // [4096][768]
    u16* wqkv = xb + (size_t)ROWS * DM;            // [2304][768]
    u16* wo   = wqkv + (size_t)NQKV * DM;          // [768][768]
    u16* Qb   = wo + (size_t)DM * DM;
    size_t hsz = (size_t)BATCH * NH * SLEN * DH;
    u16* Kb   = Qb + hsz;
    u16* Vb   = Kb + hsz;                          // V^T [b,h,d,s]
    u16* Zb   = Vb + hsz;                          // [4096][768]
    u16* Po   = Zb + (size_t)ROWS * DM;            // partials o: [24*80][64][64] bf16
    float* Pl = (float*)(Po + (size_t)BATCH * NH * NCHUNK * 4096);

    pack_x<<<ROWS * DM / 2048, 256, 0, stream>>>(x, xb);
    pack_wqkv<<<dim3(12, 12, 3), 256, 0, stream>>>(WQ, WK, WV, wqkv);
    pack_wo<<<dim3(12, 12), 256, 0, stream>>>(WO, wo);
    gemm_qkv<<<dim3(NQKV / 128, ROWS / 128), 256, 0, stream>>>(xb, wqkv, bQ, bK, bV, Qb, Kb, Vb);
    attn<<<dim3(NCHUNK * 24), 256, 0, stream>>>(Qb, Kb, Vb, Po, Pl);
    combine<<<dim3(SLEN / 64, BATCH * NH), 256, 0, stream>>>(Po, Pl, Zb);
    gemm_proj<<<dim3(DM / 96, ROWS / 64), 256, 0, stream>>>(Zb, wo, bO, out);
}

// Round 13
// 165.754 us; speedup vs baseline: 1.2236x; 1.0306x over previous
//
#include <hip/hip_runtime.h>
#include <hip/hip_bf16.h>

#define BATCH 2
#define SLEN 2048
#define NH 12
#define DM 768
#define DH 64
#define ROWS (BATCH*SLEN)   // 4096
#define NQKV (3*DM)         // 2304
#define NCHUNK 80           // split-K chunks per bh (q-tile=64, chunk = up to 8 k-tiles)

typedef __attribute__((ext_vector_type(8))) short bf16x8;
typedef __attribute__((ext_vector_type(4))) float f32x4;
typedef unsigned short u16;
typedef unsigned int u32;
typedef __attribute__((ext_vector_type(4))) unsigned short u16x4;
typedef __attribute__((ext_vector_type(8))) unsigned short u16x8;

__device__ __forceinline__ u16 f2b(float f) {
    unsigned int u = __builtin_bit_cast(unsigned int, f);
    unsigned int r = (u + 0x7FFFu + ((u >> 16) & 1u)) >> 16;
    return (u16)r;
}
__device__ __forceinline__ float b2f(u16 v) {
    unsigned int u = ((unsigned int)v) << 16;
    return __builtin_bit_cast(float, u);
}

// async global->LDS, 16B per lane. LDS dest = wave-uniform base + lane*16.
__device__ __forceinline__ void gload16(const u16* g, u16* l) {
    __builtin_amdgcn_global_load_lds(
        (const __attribute__((address_space(1))) unsigned int*)g,
        (__attribute__((address_space(3))) unsigned int*)l,
        16, 0, 0);
}

// ---------------- pack kernels ----------------

__global__ __launch_bounds__(256) void pack_x(const float* __restrict__ x, u16* __restrict__ xb) {
    int i = blockIdx.x * 256 + threadIdx.x;
    const float4* xv = (const float4*)x;
    float4 a = xv[i * 2], b = xv[i * 2 + 1];
    u16x8 o;
    o[0] = f2b(a.x); o[1] = f2b(a.y); o[2] = f2b(a.z); o[3] = f2b(a.w);
    o[4] = f2b(b.x); o[5] = f2b(b.y); o[6] = f2b(b.z); o[7] = f2b(b.w);
    *(u16x8*)(xb + (size_t)i * 8) = o;
}

__global__ __launch_bounds__(256) void pack_wqkv(const float* __restrict__ WQ, const float* __restrict__ WK,
                                                 const float* __restrict__ WV, u16* __restrict__ out) {
    __shared__ u16 L[64 * 72];
    int mt = blockIdx.x, h = blockIdx.y, sel = blockIdx.z;
    const float* W = sel == 0 ? WQ : (sel == 1 ? WK : WV);
    const float* src = W + ((size_t)h * DM + mt * 64) * DH;
    int t = threadIdx.x;
    for (int j = 0; j < 4; j++) {
        int i = t + 256 * j;
        int r = i >> 4, cf = i & 15;
        float4 v = ((const float4*)src)[i];
        u16x4 o; o[0] = f2b(v.x); o[1] = f2b(v.y); o[2] = f2b(v.z); o[3] = f2b(v.w);
        *(u16x4*)&L[r * 72 + cf * 4] = o;
    }
    __syncthreads();
    u16* orow = out + ((size_t)(sel * DM + h * DH)) * DM + mt * 64;
    for (int j = 0; j < 16; j++) {
        int e = t + 256 * j;
        int d = e >> 6, mm = e & 63;
        orow[(size_t)d * DM + mm] = L[mm * 72 + d];
    }
}

__global__ __launch_bounds__(256) void pack_wo(const float* __restrict__ WO, u16* __restrict__ out) {
    __shared__ u16 L[64 * 72];
    int bi = blockIdx.x, bj = blockIdx.y;
    int t = threadIdx.x;
    for (int j = 0; j < 4; j++) {
        int i = t + 256 * j;
        int r = i >> 4, cf = i & 15;
        float4 v = ((const float4*)(WO + (size_t)(bi * 64 + r) * DM + bj * 64))[cf];
        u16x4 o; o[0] = f2b(v.x); o[1] = f2b(v.y); o[2] = f2b(v.z); o[3] = f2b(v.w);
        *(u16x4*)&L[r * 72 + cf * 4] = o;
    }
    __syncthreads();
    for (int j = 0; j < 16; j++) {
        int e = t + 256 * j;
        int c = e >> 6, r = e & 63;
        out[(size_t)(bj * 64 + c) * DM + bi * 64 + r] = L[r * 72 + c];
    }
}

// ---------------- QKV GEMM (128x96 tile, gload16 staging, XOR-swizzled LDS) ----
// grid 24x32 = 768 blocks -> one full residency wave at 3 blocks/CU, no remainder.
// (R5's 96-tile write explosion was the preload spill, not the tile — R6 A/B.)

__global__ __launch_bounds__(256) void gemm_qkv(const u16* __restrict__ A, const u16* __restrict__ Bt,
                                                const float* __restrict__ bQ, const float* __restrict__ bK,
                                                const float* __restrict__ bV,
                                                u16* __restrict__ Qb, u16* __restrict__ Kb, u16* __restrict__ Vb) {
    __shared__ u16 Al[128 * 64];
    __shared__ u16 Bl[96 * 64];
    int t = threadIdx.x;
    int n0 = blockIdx.x * 96, m0 = blockIdx.y * 128;
    int lane = t & 63, w = t >> 6;
    int ln = lane & 15, qd = lane >> 4;
    int wr = (w & 1) * 64, wc = (w >> 1) * 48;
    int srow = lane >> 3, slot = lane & 7;
    f32x4 acc[4][3] = {};

    for (int kt = 0; kt < DM / 64; kt++) {
        __syncthreads();
        for (int j = 0; j < 4; j++) {
            int r = w * 32 + j * 8 + srow;
            int gc = slot ^ (r & 7);
            gload16(A + (size_t)(m0 + r) * DM + kt * 64 + gc * 8, &Al[(w * 32 + j * 8) * 64]);
        }
        for (int j = 0; j < 3; j++) {
            int r = w * 24 + j * 8 + srow;
            int gc = slot ^ (r & 7);
            gload16(Bt + (size_t)(n0 + r) * DM + kt * 64 + gc * 8, &Bl[(w * 24 + j * 8) * 64]);
        }
        __syncthreads();   // drains vmcnt -> tile visible
        for (int ks = 0; ks < 2; ks++) {
            int sl = ((ks * 4 + qd) ^ (ln & 7)) * 8;
            bf16x8 af[4], bfr[3];
            for (int rt = 0; rt < 4; rt++)
                af[rt] = *(const bf16x8*)&Al[(wr + rt * 16 + ln) * 64 + sl];
            for (int ct = 0; ct < 3; ct++)
                bfr[ct] = *(const bf16x8*)&Bl[(wc + ct * 16 + ln) * 64 + sl];
            for (int rt = 0; rt < 4; rt++)
                for (int ct = 0; ct < 3; ct++)
                    acc[rt][ct] = __builtin_amdgcn_mfma_f32_16x16x32_bf16(af[rt], bfr[ct], acc[rt][ct], 0, 0, 0);
        }
    }
    int sel = n0 / DM;                   // 768/96 = 8 tiles per sel -> uniform per block
    if (sel == 2) {
        for (int ct = 0; ct < 3; ct++) {
            int col = n0 - 2 * DM + wc + ct * 16 + ln;
            int hh = col >> 6, dd = col & 63;
            float bv = bV[col];
            for (int rt = 0; rt < 4; rt++) {
                int row = m0 + wr + rt * 16 + qd * 4;
                int bb = row >> 11, ss = row & 2047;
                u16x4 pk;
                for (int r = 0; r < 4; r++) pk[r] = f2b(acc[rt][ct][r] + bv);
                *(u16x4*)&Vb[(((size_t)bb * NH + hh) * DH + dd) * SLEN + ss] = pk;
            }
        }
    } else {
        const float* bias = sel == 0 ? bQ : bK;
        u16* Out = sel == 0 ? Qb : Kb;
        const float qs = sel == 0 ? 0.125f * 1.44269504f : 1.0f;
        for (int ct = 0; ct < 3; ct++) {
            int col = n0 - sel * DM + wc + ct * 16 + ln;
            int hh = col >> 6, dd = col & 63;
            float bv = bias[col];
            for (int rt = 0; rt < 4; rt++) {
                int row = m0 + wr + rt * 16 + qd * 4;
                for (int r = 0; r < 4; r++) {
                    int rg = row + r;
                    int bb = rg >> 11, ss = rg & 2047;
                    Out[(((size_t)bb * NH + hh) * SLEN + ss) * DH + dd] = f2b((acc[rt][ct][r] + bv) * qs);
                }
            }
        }
    }
}

// ---------------- split-K flash attention (R7 form) + XCD-local bh + LPT order ----
// 1D grid 1920: cid = NCHUNK-1 - blk/24 (largest chunks dispatch FIRST);
// j24 = blk%24 -> bh = (j24&7)*3 + (j24>>3) (per-XCD K/V L2 residency).

__device__ __forceinline__ void cid2qc(int cid, int& qt, int& c, int& nc) {
    if (cid < 8)       { qt = cid;                 c = 0;              nc = 1; }
    else if (cid < 24) { qt = 8 + ((cid - 8) >> 1); c = (cid - 8) & 1; nc = 2; }
    else if (cid < 48) { qt = 16 + (cid - 24) / 3;  c = (cid - 24) % 3; nc = 3; }
    else               { qt = 24 + ((cid - 48) >> 2); c = (cid - 48) & 3; nc = 4; }
}

__global__ __launch_bounds__(256, 4) void attn(const u16* __restrict__ Qb, const u16* __restrict__ Kb,
                                               const u16* __restrict__ Vtg,
                                               u16* __restrict__ Po, float* __restrict__ Plv) {
    __shared__ u16 Kl[64 * 72];
    __shared__ u16 Vt[64 * 72];          // [d][k]
    __shared__ u16 Pq[4][16 * 72];       // wave-private P: [q-local][k]
    int blk = blockIdx.x;
    int cid = (NCHUNK - 1) - blk / 24;   // largest-chunk-first (LPT)
    int j24 = blk % 24;
    int bh = (j24 & 7) * 3 + (j24 >> 3);
    int qt, c, nc;
    cid2qc(cid, qt, c, nc);
    int ntiles = qt + 1;
    int kt0 = c * ntiles / nc, kt1 = (c + 1) * ntiles / nc;
    const u16* Qp = Qb + (size_t)bh * SLEN * DH;
    const u16* Kp = Kb + (size_t)bh * SLEN * DH;
    const u16* Vp = Vtg + (size_t)bh * SLEN * DH;  // [d][s]
    int t = threadIdx.x, lane = t & 63, w = t >> 6;
    int ln = lane & 15, qd = lane >> 4;
    int qw = qt * 64 + w * 16;

    bf16x8 qf[2];
    for (int ks = 0; ks < 2; ks++)
        qf[ks] = *(const bf16x8*)(Qp + (size_t)(qw + ln) * DH + ks * 32 + qd * 8);

    float l = 0.f;
    f32x4 o[4] = {};

    u16x8 kr[2], vr[2];
    int sr = t >> 3, scf = t & 7;
    auto preload = [&](int kt) {
        int k0 = kt * 64;
        for (int j = 0; j < 2; j++) {
            int r = sr + 32 * j;
            kr[j] = *(const u16x8*)(Kp + (size_t)(k0 + r) * DH + scf * 8);
            vr[j] = *(const u16x8*)(Vp + (size_t)r * SLEN + k0 + scf * 8);
        }
    };
    preload(kt0);

    u16* Pw = Pq[w];
    for (int kt = kt0; kt < kt1; kt++) {
        __syncthreads();
        for (int j = 0; j < 2; j++) {
            int r = sr + 32 * j;
            *(u16x8*)&Kl[r * 72 + scf * 8] = kr[j];
            *(u16x8*)&Vt[r * 72 + scf * 8] = vr[j];
        }
        __syncthreads();
        if (kt + 1 < kt1) preload(kt + 1);

        f32x4 sf[4] = {};
        for (int ks = 0; ks < 2; ks++)
            for (int ct = 0; ct < 4; ct++) {
                bf16x8 kf = *(const bf16x8*)&Kl[(ct * 16 + ln) * 72 + ks * 32 + qd * 8];
                sf[ct] = __builtin_amdgcn_mfma_f32_16x16x32_bf16(kf, qf[ks], sf[ct], 0, 0, 0);
            }

        if (kt == qt) {
            int qg = qw + ln;
            for (int ct = 0; ct < 4; ct++)
                for (int r = 0; r < 4; r++) {
                    int kg = kt * 64 + ct * 16 + qd * 4 + r;
                    if (kg > qg) sf[ct][r] = -1e30f;
                }
        }

        float s = 0.f;
        for (int ct = 0; ct < 4; ct++) {
            u32 eb[4];
            for (int r = 0; r < 4; r++) {
                float e = exp2f(sf[ct][r]);
                u32 ub = __builtin_bit_cast(u32, e) & 0xFFFF0000u;
                eb[r] = __builtin_bit_cast(u32, e);
                s += __builtin_bit_cast(float, ub);
            }
            u32 p01 = __builtin_amdgcn_perm(eb[1], eb[0], 0x07060302u);
            u32 p23 = __builtin_amdgcn_perm(eb[3], eb[2], 0x07060302u);
            uint2 pk; pk.x = p01; pk.y = p23;
            *(uint2*)&Pw[ln * 72 + ct * 16 + qd * 4] = pk;
        }
        l += s;

        for (int ks = 0; ks < 2; ks++) {
            bf16x8 pf = *(const bf16x8*)&Pw[ln * 72 + ks * 32 + qd * 8];
            for (int dt = 0; dt < 4; dt++) {
                bf16x8 vf = *(const bf16x8*)&Vt[(dt * 16 + ln) * 72 + ks * 32 + qd * 8];
                o[dt] = __builtin_amdgcn_mfma_f32_16x16x32_bf16(vf, pf, o[dt], 0, 0, 0);
            }
        }
    }

    l += __shfl_xor(l, 16, 64);
    l += __shfl_xor(l, 32, 64);

    size_t pid = (size_t)bh * NCHUNK + cid;
    u16* op = Po + pid * 4096;
    for (int dt = 0; dt < 4; dt++) {
        u16x4 ov;
        ov[0] = f2b(o[dt][0]); ov[1] = f2b(o[dt][1]);
        ov[2] = f2b(o[dt][2]); ov[3] = f2b(o[dt][3]);
        *(u16x4*)&op[(w * 16 + ln) * 64 + dt * 16 + qd * 4] = ov;
    }
    if (qd == 0)
        Plv[pid * 64 + w * 16 + ln] = l;
}

// ---------------- combine partials -> Z bf16 [4096][768] ----------------

__global__ __launch_bounds__(256) void combine(const u16* __restrict__ Po, const float* __restrict__ Plv,
                                               u16* __restrict__ Zb) {
    int qt = blockIdx.x, bh = blockIdx.y;
    int b = bh / NH, h = bh % NH;
    int nc = (qt >> 3) + 1;
    int base;
    if (qt < 8) base = qt;
    else if (qt < 16) base = 8 + (qt - 8) * 2;
    else if (qt < 24) base = 24 + (qt - 16) * 3;
    else base = 48 + (qt - 24) * 4;
    int t = threadIdx.x;
    int q = t >> 2, dseg = (t & 3) * 16;

    float acc[16] = {};
    float lsum = 0.f;
    for (int cc = 0; cc < nc; cc++) {
        size_t pid = (size_t)bh * NCHUNK + base + cc;
        lsum += Plv[pid * 64 + q];
        const u16* op = Po + pid * 4096 + q * 64 + dseg;
        for (int j = 0; j < 2; j++) {
            u16x8 v = *(const u16x8*)(op + j * 8);
            for (int e = 0; e < 8; e++)
                acc[j * 8 + e] += b2f(v[e]);
        }
    }
    float inv = 1.0f / lsum;
    u16* Zp = Zb + ((size_t)b * SLEN + qt * 64 + q) * DM + h * DH + dseg;
    u16x8 ov;
    for (int j = 0; j < 2; j++) {
        for (int e = 0; e < 8; e++) ov[e] = f2b(acc[j * 8 + e] * inv);
        *(u16x8*)(Zp + j * 8) = ov;
    }
}

// ---------------- output projection (64x96 tile, global_load_lds staging) ----------------
// grid (8, 64) = 512 blocks = 2.0 blocks/CU exact.

__global__ __launch_bounds__(256) void gemm_proj(const u16* __restrict__ A, const u16* __restrict__ Bt,
                                                 const float* __restrict__ bO, float* __restrict__ out) {
    __shared__ u16 Al[64 * 64];
    __shared__ u16 Bl[96 * 64];
    int t = threadIdx.x;
    int n0 = blockIdx.x * 96, m0 = blockIdx.y * 64;
    int lane = t & 63, w = t >> 6;
    int ln = lane & 15, qd = lane >> 4;
    int wr = (w & 1) * 32, wc = (w >> 1) * 48;
    int srow = lane >> 3, slot = lane & 7;
    f32x4 acc[2][3] = {};

    for (int kt = 0; kt < DM / 64; kt++) {
        __syncthreads();
        for (int j = 0; j < 2; j++) {
            int r = w * 16 + j * 8 + srow;
            int gc = slot ^ (r & 7);
            gload16(A + (size_t)(m0 + r) * DM + kt * 64 + gc * 8, &Al[(w * 16 + j * 8) * 64]);
        }
        for (int j = 0; j < 3; j++) {
            int r = w * 24 + j * 8 + srow;
            int gc = slot ^ (r & 7);
            gload16(Bt + (size_t)(n0 + r) * DM + kt * 64 + gc * 8, &Bl[(w * 24 + j * 8) * 64]);
        }
        __syncthreads();
        for (int ks = 0; ks < 2; ks++) {
            int sl = ((ks * 4 + qd) ^ (ln & 7)) * 8;
            bf16x8 af[2], bfr[3];
            for (int rt = 0; rt < 2; rt++)
                af[rt] = *(const bf16x8*)&Al[(wr + rt * 16 + ln) * 64 + sl];
            for (int ct = 0; ct < 3; ct++)
                bfr[ct] = *(const bf16x8*)&Bl[(wc + ct * 16 + ln) * 64 + sl];
            for (int rt = 0; rt < 2; rt++)
                for (int ct = 0; ct < 3; ct++)
                    acc[rt][ct] = __builtin_amdgcn_mfma_f32_16x16x32_bf16(af[rt], bfr[ct], acc[rt][ct], 0, 0, 0);
        }
    }
    for (int ct = 0; ct < 3; ct++) {
        int col = n0 + wc + ct * 16 + ln;
        float bv = bO[col];
        for (int rt = 0; rt < 2; rt++) {
            int row = m0 + wr + rt * 16 + qd * 4;
            for (int r = 0; r < 4; r++)
                out[(size_t)(row + r) * DM + col] = acc[rt][ct][r] + bv;
        }
    }
}

// ---------------- launch ----------------

extern "C" void kernel_launch(void* const* d_in, const int* in_sizes, int n_in,
                              void* d_out, int out_size, void* d_ws, size_t ws_size,
                              hipStream_t stream) {
    const float* x  = (const float*)d_in[0];
    const float* WQ = (const float*)d_in[1];
    const float* bQ = (const float*)d_in[2];
    const float* WK = (const float*)d_in[3];
    const float* bK = (const float*)d_in[4];
    const float* WV = (const float*)d_in[5];
    const float* bV = (const float*)d_in[6];
    const float* WO = (const float*)d_in[7];
    const float* bO = (const float*)d_in[8];
    float* out = (float*)d_out;

    u16* xb   = (u16*)d_ws;                        // [4096][768]
    u16* wqkv = xb + (size_t)ROWS * DM;            // [2304][768]
    u16* wo   = wqkv + (size_t)NQKV * DM;          // [768][768]
    u16* Qb   = wo + (size_t)DM * DM;
    size_t hsz = (size_t)BATCH * NH * SLEN * DH;
    u16* Kb   = Qb + hsz;
    u16* Vb   = Kb + hsz;                          // V^T [b,h,d,s]
    u16* Zb   = Vb + hsz;                          // [4096][768]
    u16* Po   = Zb + (size_t)ROWS * DM;            // partials o: [24*80][64][64] bf16
    float* Pl = (float*)(Po + (size_t)BATCH * NH * NCHUNK * 4096);

    pack_x<<<ROWS * DM / 2048, 256, 0, stream>>>(x, xb);
    pack_wqkv<<<dim3(12, 12, 3), 256, 0, stream>>>(WQ, WK, WV, wqkv);
    pack_wo<<<dim3(12, 12), 256, 0, stream>>>(WO, wo);
    gemm_qkv<<<dim3(NQKV / 96, ROWS / 128), 256, 0, stream>>>(xb, wqkv, bQ, bK, bV, Qb, Kb, Vb);
    attn<<<dim3(NCHUNK * 24), 256, 0, stream>>>(Qb, Kb, Vb, Po, Pl);
    combine<<<dim3(SLEN / 64, BATCH * NH), 256, 0, stream>>>(Po, Pl, Zb);
    gemm_proj<<<dim3(DM / 96, ROWS / 64), 256, 0, stream>>>(Zb, wo, bO, out);
}

// Round 14
// 159.041 us; speedup vs baseline: 1.2753x; 1.0422x over previous
//
#include <hip/hip_runtime.h>
#include <hip/hip_bf16.h>

#define BATCH 2
#define SLEN 2048
#define NH 12
#define DM 768
#define DH 64
#define ROWS (BATCH*SLEN)   // 4096
#define NQKV (3*DM)         // 2304
#define NCHUNK 80           // split-K chunks per bh (q-tile=64, chunk = up to 8 k-tiles)

typedef __attribute__((ext_vector_type(8))) short bf16x8;
typedef __attribute__((ext_vector_type(4))) float f32x4;
typedef unsigned short u16;
typedef unsigned int u32;
typedef __attribute__((ext_vector_type(4))) unsigned short u16x4;
typedef __attribute__((ext_vector_type(8))) unsigned short u16x8;

__device__ __forceinline__ u16 f2b(float f) {
    unsigned int u = __builtin_bit_cast(unsigned int, f);
    unsigned int r = (u + 0x7FFFu + ((u >> 16) & 1u)) >> 16;
    return (u16)r;
}
__device__ __forceinline__ float b2f(u16 v) {
    unsigned int u = ((unsigned int)v) << 16;
    return __builtin_bit_cast(float, u);
}

// async global->LDS, 16B per lane. LDS dest = wave-uniform base + lane*16.
__device__ __forceinline__ void gload16(const u16* g, u16* l) {
    __builtin_amdgcn_global_load_lds(
        (const __attribute__((address_space(1))) unsigned int*)g,
        (__attribute__((address_space(3))) unsigned int*)l,
        16, 0, 0);
}

// ---------------- merged pack kernel (x -> bf16, W_QKV -> Bt layout, W_O -> Bt layout) ----
// grid 2112 = 1536 (x) + 432 (wqkv) + 144 (wo); branch is block-uniform.

__global__ __launch_bounds__(256) void pack_all(const float* __restrict__ x,
                                                const float* __restrict__ WQ, const float* __restrict__ WK,
                                                const float* __restrict__ WV, const float* __restrict__ WO,
                                                u16* __restrict__ xb, u16* __restrict__ wqkv,
                                                u16* __restrict__ wo) {
    __shared__ u16 L[64 * 72];
    int blk = blockIdx.x;
    int t = threadIdx.x;
    if (blk < 1536) {
        int i = blk * 256 + t;
        const float4* xv = (const float4*)x;
        float4 a = xv[i * 2], b = xv[i * 2 + 1];
        u16x8 o;
        o[0] = f2b(a.x); o[1] = f2b(a.y); o[2] = f2b(a.z); o[3] = f2b(a.w);
        o[4] = f2b(b.x); o[5] = f2b(b.y); o[6] = f2b(b.z); o[7] = f2b(b.w);
        *(u16x8*)(xb + (size_t)i * 8) = o;
    } else if (blk < 1968) {
        int idx = blk - 1536;
        int mt = idx % 12, h = (idx / 12) % 12, sel = idx / 144;
        const float* W = sel == 0 ? WQ : (sel == 1 ? WK : WV);
        const float* src = W + ((size_t)h * DM + mt * 64) * DH;
        for (int j = 0; j < 4; j++) {
            int i = t + 256 * j;
            int r = i >> 4, cf = i & 15;
            float4 v = ((const float4*)src)[i];
            u16x4 o; o[0] = f2b(v.x); o[1] = f2b(v.y); o[2] = f2b(v.z); o[3] = f2b(v.w);
            *(u16x4*)&L[r * 72 + cf * 4] = o;
        }
        __syncthreads();
        u16* orow = wqkv + ((size_t)(sel * DM + h * DH)) * DM + mt * 64;
        for (int j = 0; j < 16; j++) {
            int e = t + 256 * j;
            int d = e >> 6, mm = e & 63;
            orow[(size_t)d * DM + mm] = L[mm * 72 + d];
        }
    } else {
        int idx = blk - 1968;
        int bi = idx % 12, bj = idx / 12;
        for (int j = 0; j < 4; j++) {
            int i = t + 256 * j;
            int r = i >> 4, cf = i & 15;
            float4 v = ((const float4*)(WO + (size_t)(bi * 64 + r) * DM + bj * 64))[cf];
            u16x4 o; o[0] = f2b(v.x); o[1] = f2b(v.y); o[2] = f2b(v.z); o[3] = f2b(v.w);
            *(u16x4*)&L[r * 72 + cf * 4] = o;
        }
        __syncthreads();
        for (int j = 0; j < 16; j++) {
            int e = t + 256 * j;
            int c = e >> 6, r = e & 63;
            wo[(size_t)(bj * 64 + c) * DM + bi * 64 + r] = L[r * 72 + c];
        }
    }
}

// ---------------- QKV GEMM (128x96 tile, gload16 staging, XOR-swizzled LDS) ----
// grid 24x32 = 768 blocks -> one full residency wave at 3 blocks/CU, no remainder.

__global__ __launch_bounds__(256) void gemm_qkv(const u16* __restrict__ A, const u16* __restrict__ Bt,
                                                const float* __restrict__ bQ, const float* __restrict__ bK,
                                                const float* __restrict__ bV,
                                                u16* __restrict__ Qb, u16* __restrict__ Kb, u16* __restrict__ Vb) {
    __shared__ u16 Al[128 * 64];
    __shared__ u16 Bl[96 * 64];
    int t = threadIdx.x;
    int n0 = blockIdx.x * 96, m0 = blockIdx.y * 128;
    int lane = t & 63, w = t >> 6;
    int ln = lane & 15, qd = lane >> 4;
    int wr = (w & 1) * 64, wc = (w >> 1) * 48;
    int srow = lane >> 3, slot = lane & 7;
    f32x4 acc[4][3] = {};

    for (int kt = 0; kt < DM / 64; kt++) {
        __syncthreads();
        for (int j = 0; j < 4; j++) {
            int r = w * 32 + j * 8 + srow;
            int gc = slot ^ (r & 7);
            gload16(A + (size_t)(m0 + r) * DM + kt * 64 + gc * 8, &Al[(w * 32 + j * 8) * 64]);
        }
        for (int j = 0; j < 3; j++) {
            int r = w * 24 + j * 8 + srow;
            int gc = slot ^ (r & 7);
            gload16(Bt + (size_t)(n0 + r) * DM + kt * 64 + gc * 8, &Bl[(w * 24 + j * 8) * 64]);
        }
        __syncthreads();   // drains vmcnt -> tile visible
        for (int ks = 0; ks < 2; ks++) {
            int sl = ((ks * 4 + qd) ^ (ln & 7)) * 8;
            bf16x8 af[4], bfr[3];
            for (int rt = 0; rt < 4; rt++)
                af[rt] = *(const bf16x8*)&Al[(wr + rt * 16 + ln) * 64 + sl];
            for (int ct = 0; ct < 3; ct++)
                bfr[ct] = *(const bf16x8*)&Bl[(wc + ct * 16 + ln) * 64 + sl];
            for (int rt = 0; rt < 4; rt++)
                for (int ct = 0; ct < 3; ct++)
                    acc[rt][ct] = __builtin_amdgcn_mfma_f32_16x16x32_bf16(af[rt], bfr[ct], acc[rt][ct], 0, 0, 0);
        }
    }
    int sel = n0 / DM;                   // 768/96 = 8 tiles per sel -> uniform per block
    if (sel == 2) {
        for (int ct = 0; ct < 3; ct++) {
            int col = n0 - 2 * DM + wc + ct * 16 + ln;
            int hh = col >> 6, dd = col & 63;
            float bv = bV[col];
            for (int rt = 0; rt < 4; rt++) {
                int row = m0 + wr + rt * 16 + qd * 4;
                int bb = row >> 11, ss = row & 2047;
                u16x4 pk;
                for (int r = 0; r < 4; r++) pk[r] = f2b(acc[rt][ct][r] + bv);
                *(u16x4*)&Vb[(((size_t)bb * NH + hh) * DH + dd) * SLEN + ss] = pk;
            }
        }
    } else {
        const float* bias = sel == 0 ? bQ : bK;
        u16* Out = sel == 0 ? Qb : Kb;
        const float qs = sel == 0 ? 0.125f * 1.44269504f : 1.0f;
        for (int ct = 0; ct < 3; ct++) {
            int col = n0 - sel * DM + wc + ct * 16 + ln;
            int hh = col >> 6, dd = col & 63;
            float bv = bias[col];
            for (int rt = 0; rt < 4; rt++) {
                int row = m0 + wr + rt * 16 + qd * 4;
                for (int r = 0; r < 4; r++) {
                    int rg = row + r;
                    int bb = rg >> 11, ss = rg & 2047;
                    Out[(((size_t)bb * NH + hh) * SLEN + ss) * DH + dd] = f2b((acc[rt][ct][r] + bv) * qs);
                }
            }
        }
    }
}

// ---------------- split-K flash attention: XCD-local bh, LPT order, MFMA l-sum ----
// 1D grid 1920: cid = NCHUNK-1 - blk/24 (largest chunks first);
// bh = (blk%24&7)*3 + (blk%24>>3) (per-XCD K/V L2 residency).
// l accumulated via ones-row MFMA on truncated P (bit-consistent with PV numerator).

__device__ __forceinline__ void cid2qc(int cid, int& qt, int& c, int& nc) {
    if (cid < 8)       { qt = cid;                 c = 0;              nc = 1; }
    else if (cid < 24) { qt = 8 + ((cid - 8) >> 1); c = (cid - 8) & 1; nc = 2; }
    else if (cid < 48) { qt = 16 + (cid - 24) / 3;  c = (cid - 24) % 3; nc = 3; }
    else               { qt = 24 + ((cid - 48) >> 2); c = (cid - 48) & 3; nc = 4; }
}

__global__ __launch_bounds__(256, 4) void attn(const u16* __restrict__ Qb, const u16* __restrict__ Kb,
                                               const u16* __restrict__ Vtg,
                                               u16* __restrict__ Po, float* __restrict__ Plv) {
    __shared__ u16 Kl[64 * 72];
    __shared__ u16 Vt[64 * 72];          // [d][k]
    __shared__ u16 Pq[4][16 * 72];       // wave-private P: [q-local][k]
    int blk = blockIdx.x;
    int cid = (NCHUNK - 1) - blk / 24;   // largest-chunk-first (LPT)
    int j24 = blk % 24;
    int bh = (j24 & 7) * 3 + (j24 >> 3);
    int qt, c, nc;
    cid2qc(cid, qt, c, nc);
    int ntiles = qt + 1;
    int kt0 = c * ntiles / nc, kt1 = (c + 1) * ntiles / nc;
    const u16* Qp = Qb + (size_t)bh * SLEN * DH;
    const u16* Kp = Kb + (size_t)bh * SLEN * DH;
    const u16* Vp = Vtg + (size_t)bh * SLEN * DH;  // [d][s]
    int t = threadIdx.x, lane = t & 63, w = t >> 6;
    int ln = lane & 15, qd = lane >> 4;
    int qw = qt * 64 + w * 16;

    bf16x8 qf[2];
    for (int ks = 0; ks < 2; ks++)
        qf[ks] = *(const bf16x8*)(Qp + (size_t)(qw + ln) * DH + ks * 32 + qd * 8);

    bf16x8 onesf;
    for (int e = 0; e < 8; e++) onesf[e] = (short)0x3F80;   // bf16 1.0

    f32x4 o[4] = {};
    f32x4 oL = {};                        // l accumulator (col q = ln, rows identical)

    u16x8 kr[2], vr[2];
    int sr = t >> 3, scf = t & 7;
    auto preload = [&](int kt) {
        int k0 = kt * 64;
        for (int j = 0; j < 2; j++) {
            int r = sr + 32 * j;
            kr[j] = *(const u16x8*)(Kp + (size_t)(k0 + r) * DH + scf * 8);
            vr[j] = *(const u16x8*)(Vp + (size_t)r * SLEN + k0 + scf * 8);
        }
    };
    preload(kt0);

    u16* Pw = Pq[w];
    for (int kt = kt0; kt < kt1; kt++) {
        __syncthreads();
        for (int j = 0; j < 2; j++) {
            int r = sr + 32 * j;
            *(u16x8*)&Kl[r * 72 + scf * 8] = kr[j];
            *(u16x8*)&Vt[r * 72 + scf * 8] = vr[j];
        }
        __syncthreads();
        if (kt + 1 < kt1) preload(kt + 1);

        f32x4 sf[4] = {};
        for (int ks = 0; ks < 2; ks++)
            for (int ct = 0; ct < 4; ct++) {
                bf16x8 kf = *(const bf16x8*)&Kl[(ct * 16 + ln) * 72 + ks * 32 + qd * 8];
                sf[ct] = __builtin_amdgcn_mfma_f32_16x16x32_bf16(kf, qf[ks], sf[ct], 0, 0, 0);
            }

        if (kt == qt) {
            int qg = qw + ln;
            for (int ct = 0; ct < 4; ct++)
                for (int r = 0; r < 4; r++) {
                    int kg = kt * 64 + ct * 16 + qd * 4 + r;
                    if (kg > qg) sf[ct][r] = -1e30f;
                }
        }

        // exp2 + truncate-to-bf16 pack via v_perm (picks high 16 bits = truncation)
        for (int ct = 0; ct < 4; ct++) {
            u32 eb[4];
            for (int r = 0; r < 4; r++)
                eb[r] = __builtin_bit_cast(u32, exp2f(sf[ct][r]));
            uint2 pk;
            pk.x = __builtin_amdgcn_perm(eb[1], eb[0], 0x07060302u);
            pk.y = __builtin_amdgcn_perm(eb[3], eb[2], 0x07060302u);
            *(uint2*)&Pw[ln * 72 + ct * 16 + qd * 4] = pk;
        }

        // Z^T += V^T P^T; l += 1^T P^T (MFMA pipe, bit-consistent with PV)
        for (int ks = 0; ks < 2; ks++) {
            bf16x8 pf = *(const bf16x8*)&Pw[ln * 72 + ks * 32 + qd * 8];
            oL = __builtin_amdgcn_mfma_f32_16x16x32_bf16(onesf, pf, oL, 0, 0, 0);
            for (int dt = 0; dt < 4; dt++) {
                bf16x8 vf = *(const bf16x8*)&Vt[(dt * 16 + ln) * 72 + ks * 32 + qd * 8];
                o[dt] = __builtin_amdgcn_mfma_f32_16x16x32_bf16(vf, pf, o[dt], 0, 0, 0);
            }
        }
    }

    size_t pid = (size_t)bh * NCHUNK + cid;
    u16* op = Po + pid * 4096;
    for (int dt = 0; dt < 4; dt++) {
        u16x4 ov;
        ov[0] = f2b(o[dt][0]); ov[1] = f2b(o[dt][1]);
        ov[2] = f2b(o[dt][2]); ov[3] = f2b(o[dt][3]);
        *(u16x4*)&op[(w * 16 + ln) * 64 + dt * 16 + qd * 4] = ov;
    }
    if (qd == 0)
        Plv[pid * 64 + w * 16 + ln] = oL[0];   // full k-sum for q=ln (rows identical)
}

// ---------------- combine partials -> Z bf16 [4096][768] ----------------

__global__ __launch_bounds__(256) void combine(const u16* __restrict__ Po, const float* __restrict__ Plv,
                                               u16* __restrict__ Zb) {
    int qt = blockIdx.x, bh = blockIdx.y;
    int b = bh / NH, h = bh % NH;
    int nc = (qt >> 3) + 1;
    int base;
    if (qt < 8) base = qt;
    else if (qt < 16) base = 8 + (qt - 8) * 2;
    else if (qt < 24) base = 24 + (qt - 16) * 3;
    else base = 48 + (qt - 24) * 4;
    int t = threadIdx.x;
    int q = t >> 2, dseg = (t & 3) * 16;

    float acc[16] = {};
    float lsum = 0.f;
    for (int cc = 0; cc < nc; cc++) {
        size_t pid = (size_t)bh * NCHUNK + base + cc;
        lsum += Plv[pid * 64 + q];
        const u16* op = Po + pid * 4096 + q * 64 + dseg;
        for (int j = 0; j < 2; j++) {
            u16x8 v = *(const u16x8*)(op + j * 8);
            for (int e = 0; e < 8; e++)
                acc[j * 8 + e] += b2f(v[e]);
        }
    }
    float inv = 1.0f / lsum;
    u16* Zp = Zb + ((size_t)b * SLEN + qt * 64 + q) * DM + h * DH + dseg;
    u16x8 ov;
    for (int j = 0; j < 2; j++) {
        for (int e = 0; e < 8; e++) ov[e] = f2b(acc[j * 8 + e] * inv);
        *(u16x8*)(Zp + j * 8) = ov;
    }
}

// ---------------- output projection (64x96 tile, global_load_lds staging) ----------------
// grid (8, 64) = 512 blocks = 2.0 blocks/CU exact.

__global__ __launch_bounds__(256) void gemm_proj(const u16* __restrict__ A, const u16* __restrict__ Bt,
                                                 const float* __restrict__ bO, float* __restrict__ out) {
    __shared__ u16 Al[64 * 64];
    __shared__ u16 Bl[96 * 64];
    int t = threadIdx.x;
    int n0 = blockIdx.x * 96, m0 = blockIdx.y * 64;
    int lane = t & 63, w = t >> 6;
    int ln = lane & 15, qd = lane >> 4;
    int wr = (w & 1) * 32, wc = (w >> 1) * 48;
    int srow = lane >> 3, slot = lane & 7;
    f32x4 acc[2][3] = {};

    for (int kt = 0; kt < DM / 64; kt++) {
        __syncthreads();
        for (int j = 0; j < 2; j++) {
            int r = w * 16 + j * 8 + srow;
            int gc = slot ^ (r & 7);
            gload16(A + (size_t)(m0 + r) * DM + kt * 64 + gc * 8, &Al[(w * 16 + j * 8) * 64]);
        }
        for (int j = 0; j < 3; j++) {
            int r = w * 24 + j * 8 + srow;
            int gc = slot ^ (r & 7);
            gload16(Bt + (size_t)(n0 + r) * DM + kt * 64 + gc * 8, &Bl[(w * 24 + j * 8) * 64]);
        }
        __syncthreads();
        for (int ks = 0; ks < 2; ks++) {
            int sl = ((ks * 4 + qd) ^ (ln & 7)) * 8;
            bf16x8 af[2], bfr[3];
            for (int rt = 0; rt < 2; rt++)
                af[rt] = *(const bf16x8*)&Al[(wr + rt * 16 + ln) * 64 + sl];
            for (int ct = 0; ct < 3; ct++)
                bfr[ct] = *(const bf16x8*)&Bl[(wc + ct * 16 + ln) * 64 + sl];
            for (int rt = 0; rt < 2; rt++)
                for (int ct = 0; ct < 3; ct++)
                    acc[rt][ct] = __builtin_amdgcn_mfma_f32_16x16x32_bf16(af[rt], bfr[ct], acc[rt][ct], 0, 0, 0);
        }
    }
    for (int ct = 0; ct < 3; ct++) {
        int col = n0 + wc + ct * 16 + ln;
        float bv = bO[col];
        for (int rt = 0; rt < 2; rt++) {
            int row = m0 + wr + rt * 16 + qd * 4;
            for (int r = 0; r < 4; r++)
                out[(size_t)(row + r) * DM + col] = acc[rt][ct][r] + bv;
        }
    }
}

// ---------------- launch ----------------

extern "C" void kernel_launch(void* const* d_in, const int* in_sizes, int n_in,
                              void* d_out, int out_size, void* d_ws, size_t ws_size,
                              hipStream_t stream) {
    const float* x  = (const float*)d_in[0];
    const float* WQ = (const float*)d_in[1];
    const float* bQ = (const float*)d_in[2];
    const float* WK = (const float*)d_in[3];
    const float* bK = (const float*)d_in[4];
    const float* WV = (const float*)d_in[5];
    const float* bV = (const float*)d_in[6];
    const float* WO = (const float*)d_in[7];
    const float* bO = (const float*)d_in[8];
    float* out = (float*)d_out;

    u16* xb   = (u16*)d_ws;                        // [4096][768]
    u16* wqkv = xb + (size_t)ROWS * DM;            // [2304][768]
    u16* wo   = wqkv + (size_t)NQKV * DM;          // [768][768]
    u16* Qb   = wo + (size_t)DM * DM;
    size_t hsz = (size_t)BATCH * NH * SLEN * DH;
    u16* Kb   = Qb + hsz;
    u16* Vb   = Kb + hsz;                          // V^T [b,h,d,s]
    u16* Zb   = Vb + hsz;                          // [4096][768]
    u16* Po   = Zb + (size_t)ROWS * DM;            // partials o: [24*80][64][64] bf16
    float* Pl = (float*)(Po + (size_t)BATCH * NH * NCHUNK * 4096);

    pack_all<<<2112, 256, 0, stream>>>(x, WQ, WK, WV, WO, xb, wqkv, wo);
    gemm_qkv<<<dim3(NQKV / 96, ROWS / 128), 256, 0, stream>>>(xb, wqkv, bQ, bK, bV, Qb, Kb, Vb);
    attn<<<dim3(NCHUNK * 24), 256, 0, stream>>>(Qb, Kb, Vb, Po, Pl);
    combine<<<dim3(SLEN / 64, BATCH * NH), 256, 0, stream>>>(Po, Pl, Zb);
    gemm_proj<<<dim3(DM / 96, ROWS / 64), 256, 0, stream>>>(Zb, wo, bO, out);
}